// Round 8
// baseline (511.941 us; speedup 1.0000x reference)
//
#include <hip/hip_runtime.h>
#include <hip/hip_bf16.h>
#include <stdint.h>
#include <math.h>

// ---------------------------------------------------------------------------
// Attention_74852690035363 — f32 I/O, bf16 MFMA compute.
//   front = casts + all weight transposes + brot  [ONE z-routed launch]
//   Mprep = M GEMM (512 blk) + Wrot/tsrT prep (1024 blk)  [ONE launch]
//   x2    = hs·M (M symmetric)          [64x128 tile, BK=128]
//   mixed = x2·Wrotᵀ + brot             [128² tile BK=64, 768 blk]
//   vT    = transpose of V blocks of mixed
//   flash = fused exp(scale·q·kᵀ) causal / rowsum / P·V -> ctx
//   out   = ctx·tsrTᵀ + dense_b         [64x128 tile, BK=128, f32 store]
// LDS tiles 16B-chunk XOR-swizzled (verified: SQ_LDS_BANK_CONFLICT = 0).
// ---------------------------------------------------------------------------

typedef __bf16 bf16_t;
typedef __bf16 bf16x8 __attribute__((ext_vector_type(8)));
typedef __bf16 bf16x4 __attribute__((ext_vector_type(4)));
typedef float  f32x4  __attribute__((ext_vector_type(4)));

__device__ __forceinline__ void async16(const void* g, void* l) {
  __builtin_amdgcn_global_load_lds(
      (const __attribute__((address_space(1))) void*)(uintptr_t)g,
      (__attribute__((address_space(3))) void*)(uint32_t)(uintptr_t)l,
      16, 0, 0);
}

// ---------------- 128x128-tile NT GEMM, BK=64 (for `mixed`) ----------------
// flags&8: bf16 bias
__global__ __launch_bounds__(256)
void gemm_nt128(const bf16_t* __restrict__ A, const bf16_t* __restrict__ B,
                void* __restrict__ Cv, const void* __restrict__ biasv,
                int K, int lda, int ldb, int ldc, float alpha, int flags)
{
  const int bm0 = blockIdx.y * 128;
  const int bn0 = blockIdx.x * 128;

  __shared__ bf16_t shA[8192];   // 2 halves x 128x32
  __shared__ bf16_t shB[8192];

  const int t  = threadIdx.x;
  const int w  = t >> 6;
  const int l  = t & 63;
  const int wm = (w >> 1) * 64;
  const int wn = (w & 1) * 64;
  const int r0 = l >> 2;
  const int c0 = ((l & 3) ^ ((l >> 3) & 3)) * 8;
  const int fr = l & 15;
  const int kc = l >> 4;
  const int swr = ((fr >> 1) & 3);

  f32x4 acc[4][4];
  #pragma unroll
  for (int i = 0; i < 4; ++i)
    #pragma unroll
    for (int j = 0; j < 4; ++j)
      #pragma unroll
      for (int r = 0; r < 4; ++r)
        acc[i][j][r] = 0.0f;

  for (int k0 = 0; k0 < K; k0 += 64) {
    #pragma unroll
    for (int u = 0; u < 4; ++u) {
      const int seg  = u * 4 + w;
      const int half = seg >> 3;
      const int s8   = seg & 7;
      const int row  = s8 * 16 + r0;
      const int gk   = k0 + half * 32 + c0;
      async16(A + (long long)(bm0 + row) * lda + gk, &shA[half * 4096 + s8 * 512]);
      async16(B + (long long)(bn0 + row) * ldb + gk, &shB[half * 4096 + s8 * 512]);
    }
    __builtin_amdgcn_s_waitcnt(0);
    __syncthreads();

    const int rc = (kc ^ swr) * 8;
    #pragma unroll
    for (int h = 0; h < 2; ++h) {
      bf16x8 af[4], bfv[4];
      #pragma unroll
      for (int i = 0; i < 4; ++i) {
        af[i]  = *(const bf16x8*)&shA[h * 4096 + (wm + i * 16 + fr) * 32 + rc];
        bfv[i] = *(const bf16x8*)&shB[h * 4096 + (wn + i * 16 + fr) * 32 + rc];
      }
      #pragma unroll
      for (int i = 0; i < 4; ++i)
        #pragma unroll
        for (int j = 0; j < 4; ++j)
          acc[i][j] = __builtin_amdgcn_mfma_f32_16x16x32_bf16(af[i], bfv[j], acc[i][j], 0, 0, 0);
    }
    __syncthreads();
  }

  const int cc = l & 15;
  const int rq = (l >> 4) * 4;
  bf16_t* C = (bf16_t*)Cv;
  const bf16_t* bias = (flags & 8) ? (const bf16_t*)biasv : nullptr;
  #pragma unroll
  for (int j = 0; j < 4; ++j) {
    const int col = bn0 + wn + j * 16 + cc;
    const float bv = bias ? (float)bias[col] : 0.0f;
    #pragma unroll
    for (int i = 0; i < 4; ++i)
      #pragma unroll
      for (int r = 0; r < 4; ++r) {
        const int row = bm0 + wm + i * 16 + rq + r;
        C[(long long)row * ldc + col] = (bf16_t)(acc[i][j][r] * alpha + bv);
      }
  }
}

// ---------------- 64x128-tile NT GEMM, BK=128 (x2 / out) -------------------
// flags&4: f32 C + f32 bias
__global__ __launch_bounds__(256)
void gemm_nt64k(const bf16_t* __restrict__ A, const bf16_t* __restrict__ B,
                void* __restrict__ Cv, const void* __restrict__ biasv,
                int K, int lda, int ldb, int ldc, float alpha, int flags)
{
  const int bm0 = blockIdx.y * 64;
  const int bn0 = blockIdx.x * 128;

  __shared__ bf16_t shA[8192];    // 4 quarters x 64x32   (16 KB)
  __shared__ bf16_t shB[16384];   // 4 quarters x 128x32  (32 KB)

  const int t  = threadIdx.x;
  const int w  = t >> 6;
  const int l  = t & 63;
  const int wm = (w >> 1) * 32;
  const int wn = (w & 1) * 64;
  const int r0 = l >> 2;
  const int c0 = ((l & 3) ^ ((l >> 3) & 3)) * 8;
  const int fr = l & 15;
  const int kc = l >> 4;
  const int swr = ((fr >> 1) & 3);

  f32x4 acc[2][4];
  #pragma unroll
  for (int i = 0; i < 2; ++i)
    #pragma unroll
    for (int j = 0; j < 4; ++j)
      #pragma unroll
      for (int r = 0; r < 4; ++r)
        acc[i][j][r] = 0.0f;

  for (int k0 = 0; k0 < K; k0 += 128) {
    #pragma unroll
    for (int u = 0; u < 4; ++u) {          // A: 16 segs (4 quarters x 4)
      const int seg = u * 4 + w;
      const int q   = seg >> 2;
      const int s4  = seg & 3;
      async16(A + (long long)(bm0 + s4 * 16 + r0) * lda + (k0 + q * 32 + c0),
              &shA[q * 2048 + s4 * 512]);
    }
    #pragma unroll
    for (int u = 0; u < 8; ++u) {          // B: 32 segs (4 quarters x 8)
      const int seg = u * 4 + w;
      const int q   = seg >> 3;
      const int s8  = seg & 7;
      async16(B + (long long)(bn0 + s8 * 16 + r0) * ldb + (k0 + q * 32 + c0),
              &shB[q * 4096 + s8 * 512]);
    }
    __builtin_amdgcn_s_waitcnt(0);
    __syncthreads();

    const int rc = (kc ^ swr) * 8;
    #pragma unroll
    for (int q = 0; q < 4; ++q) {
      bf16x8 af[2], bfv[4];
      #pragma unroll
      for (int i = 0; i < 2; ++i)
        af[i]  = *(const bf16x8*)&shA[q * 2048 + (wm + i * 16 + fr) * 32 + rc];
      #pragma unroll
      for (int j = 0; j < 4; ++j)
        bfv[j] = *(const bf16x8*)&shB[q * 4096 + (wn + j * 16 + fr) * 32 + rc];
      #pragma unroll
      for (int i = 0; i < 2; ++i)
        #pragma unroll
        for (int j = 0; j < 4; ++j)
          acc[i][j] = __builtin_amdgcn_mfma_f32_16x16x32_bf16(af[i], bfv[j], acc[i][j], 0, 0, 0);
    }
    __syncthreads();
  }

  const int cc = l & 15;
  const int rq = (l >> 4) * 4;
  if (flags & 4) {
    float* C = (float*)Cv;
    const float* bias = (const float*)biasv;
    #pragma unroll
    for (int j = 0; j < 4; ++j) {
      const int col = bn0 + wn + j * 16 + cc;
      const float bv = bias ? bias[col] : 0.0f;
      #pragma unroll
      for (int i = 0; i < 2; ++i)
        #pragma unroll
        for (int r = 0; r < 4; ++r) {
          const int row = bm0 + wm + i * 16 + rq + r;
          C[(long long)row * ldc + col] = acc[i][j][r] * alpha + bv;
        }
    }
  } else {
    bf16_t* C = (bf16_t*)Cv;
    #pragma unroll
    for (int j = 0; j < 4; ++j) {
      const int col = bn0 + wn + j * 16 + cc;
      #pragma unroll
      for (int i = 0; i < 2; ++i)
        #pragma unroll
        for (int r = 0; r < 4; ++r) {
          const int row = bm0 + wm + i * 16 + rq + r;
          C[(long long)row * ldc + col] = (bf16_t)(acc[i][j][r] * alpha);
        }
    }
  }
}

// ---------------- merged M GEMM + prep GEMMs (one launch) ------------------
// z < 1024: prep blocks — pz = z>>4 batch, px = z&15
//   pz<48 (pz=3h+p): Wrot[pz*128+m][n] = sum_d Rot[h][d][m]*qkv_w[128pz+d][n]
//   pz>=48 (b=pz-48): tsrT[o][b*128+e] = sum_d dwT[b][o][d]*vlT[b][e][d]
//   (128x128 tile, BK=64, K=128)
// z >= 1024: M blocks — m = z-1024: Mbuf = stb·stbᵀ (64x128 tile, BK=64)
__global__ __launch_bounds__(256)
void gemm_mprep(const bf16_t* __restrict__ qkT, const bf16_t* __restrict__ vlT,
                const bf16_t* __restrict__ qkv_wT, const bf16_t* __restrict__ dwT,
                bf16_t* __restrict__ Wrot, bf16_t* __restrict__ tsrT,
                const bf16_t* __restrict__ stb, bf16_t* __restrict__ Mbuf)
{
  __shared__ bf16_t smem[16384];   // 32 KB, carved per branch
  const int z = blockIdx.x;
  const int t  = threadIdx.x;
  const int w  = t >> 6;
  const int l  = t & 63;
  const int r0 = l >> 2;
  const int c0 = ((l & 3) ^ ((l >> 3) & 3)) * 8;
  const int fr = l & 15;
  const int kc = l >> 4;
  const int swr = ((fr >> 1) & 3);
  const int cc = l & 15;
  const int rq = (l >> 4) * 4;

  if (z < 1024) {
    // ---------------- prep body: 128x128, BK=64, K=128 ----------------
    const int pz = z >> 4, px = z & 15;
    const bf16_t* A;
    const bf16_t* B;
    bf16_t* C;
    int bm0, bn0;
    if (pz < 48) {
      const int h = pz / 3, p = pz - 3 * h;
      A = (p == 2 ? vlT : qkT) + h * 16384;
      B = qkv_wT + (long long)pz * 262144;
      C = Wrot + (long long)pz * 262144;
      bm0 = 0;  bn0 = px * 128;
    } else {
      const int b = pz - 48;
      A = dwT + (long long)b * 262144;
      B = vlT + b * 16384;
      C = tsrT;
      bm0 = px * 128;  bn0 = b * 128;
    }
    bf16_t* shA = smem;          // 8192
    bf16_t* shB = smem + 8192;   // 8192
    const int wm = (w >> 1) * 64;
    const int wn = (w & 1) * 64;
    const int arow0 = (pz < 48 ? 0 : bm0);
    const int brow0 = (pz < 48 ? bn0 : 0);

    f32x4 acc[4][4];
    #pragma unroll
    for (int i = 0; i < 4; ++i)
      #pragma unroll
      for (int j = 0; j < 4; ++j)
        #pragma unroll
        for (int r = 0; r < 4; ++r)
          acc[i][j][r] = 0.0f;

    for (int k0 = 0; k0 < 128; k0 += 64) {
      #pragma unroll
      for (int u = 0; u < 4; ++u) {
        const int seg  = u * 4 + w;
        const int half = seg >> 3;
        const int s8   = seg & 7;
        const int row  = s8 * 16 + r0;
        const int gk   = k0 + half * 32 + c0;
        async16(A + (long long)(arow0 + row) * 128 + gk, &shA[half * 4096 + s8 * 512]);
        async16(B + (long long)(brow0 + row) * 128 + gk, &shB[half * 4096 + s8 * 512]);
      }
      __builtin_amdgcn_s_waitcnt(0);
      __syncthreads();

      const int rc = (kc ^ swr) * 8;
      #pragma unroll
      for (int h = 0; h < 2; ++h) {
        bf16x8 af[4], bfv[4];
        #pragma unroll
        for (int i = 0; i < 4; ++i) {
          af[i]  = *(const bf16x8*)&shA[h * 4096 + (wm + i * 16 + fr) * 32 + rc];
          bfv[i] = *(const bf16x8*)&shB[h * 4096 + (wn + i * 16 + fr) * 32 + rc];
        }
        #pragma unroll
        for (int i = 0; i < 4; ++i)
          #pragma unroll
          for (int j = 0; j < 4; ++j)
            acc[i][j] = __builtin_amdgcn_mfma_f32_16x16x32_bf16(af[i], bfv[j], acc[i][j], 0, 0, 0);
      }
      __syncthreads();
    }

    #pragma unroll
    for (int j = 0; j < 4; ++j) {
      const int col = bn0 + wn + j * 16 + cc;
      #pragma unroll
      for (int i = 0; i < 4; ++i)
        #pragma unroll
        for (int r = 0; r < 4; ++r) {
          const int row = arow0 + wm + i * 16 + rq + r;
          C[(long long)row * 2048 + col] = (bf16_t)acc[i][j][r];
        }
    }
  } else {
    // ---------------- M body: 64x128, BK=64, K=2048, stb·stbᵀ ----------
    const int m = z - 1024;
    const int bm0 = (m >> 4) * 64;
    const int bn0 = (m & 15) * 128;
    bf16_t* shA = smem;          // 4096
    bf16_t* shB = smem + 4096;   // 8192
    const int wm = (w >> 1) * 32;
    const int wn = (w & 1) * 64;

    f32x4 acc[2][4];
    #pragma unroll
    for (int i = 0; i < 2; ++i)
      #pragma unroll
      for (int j = 0; j < 4; ++j)
        #pragma unroll
        for (int r = 0; r < 4; ++r)
          acc[i][j][r] = 0.0f;

    for (int k0 = 0; k0 < 2048; k0 += 64) {
      #pragma unroll
      for (int u = 0; u < 2; ++u) {
        const int seg  = u * 4 + w;
        const int half = seg >> 2;
        const int s4   = seg & 3;
        async16(stb + (long long)(bm0 + s4 * 16 + r0) * 2048 + (k0 + half * 32 + c0),
                &shA[half * 2048 + s4 * 512]);
      }
      #pragma unroll
      for (int u = 0; u < 4; ++u) {
        const int seg  = u * 4 + w;
        const int half = seg >> 3;
        const int s8   = seg & 7;
        async16(stb + (long long)(bn0 + s8 * 16 + r0) * 2048 + (k0 + half * 32 + c0),
                &shB[half * 4096 + s8 * 512]);
      }
      __builtin_amdgcn_s_waitcnt(0);
      __syncthreads();

      const int rc = (kc ^ swr) * 8;
      #pragma unroll
      for (int h = 0; h < 2; ++h) {
        bf16x8 af[2], bfv[4];
        #pragma unroll
        for (int i = 0; i < 2; ++i)
          af[i]  = *(const bf16x8*)&shA[h * 2048 + (wm + i * 16 + fr) * 32 + rc];
        #pragma unroll
        for (int j = 0; j < 4; ++j)
          bfv[j] = *(const bf16x8*)&shB[h * 4096 + (wn + j * 16 + fr) * 32 + rc];
        #pragma unroll
        for (int i = 0; i < 2; ++i)
          #pragma unroll
          for (int j = 0; j < 4; ++j)
            acc[i][j] = __builtin_amdgcn_mfma_f32_16x16x32_bf16(af[i], bfv[j], acc[i][j], 0, 0, 0);
      }
      __syncthreads();
    }

    #pragma unroll
    for (int j = 0; j < 4; ++j) {
      const int col = bn0 + wn + j * 16 + cc;
      #pragma unroll
      for (int i = 0; i < 2; ++i)
        #pragma unroll
        for (int r = 0; r < 4; ++r) {
          const int row = bm0 + wm + i * 16 + rq + r;
          Mbuf[(long long)row * 2048 + col] = (bf16_t)acc[i][j][r];
        }
    }
  }
}

// ---------------------------------------------------------------------------
// Flash attention (verified rounds 4-7): one block = 64 q-rows x one head.
// ---------------------------------------------------------------------------
__global__ __launch_bounds__(256)
void flash_k(const bf16_t* __restrict__ mixed, const bf16_t* __restrict__ vT,
             bf16_t* __restrict__ ctx, float iscale)
{
  const int h  = blockIdx.y;
  const int qt = 31 - (int)blockIdx.x;
  const int r0g = qt * 64;
  const int niter = (qt >> 1) + 1;
  const bf16_t* Qp = mixed + h * 384;
  const bf16_t* Kp = mixed + h * 384 + 128;
  const bf16_t* Vp = vT + (long long)h * 262144;

  __shared__ bf16_t sKV[128 * 128];
  __shared__ bf16_t sP[64 * 136];
  __shared__ float  sL[2][64];

  const int t  = threadIdx.x;
  const int w  = t >> 6;
  const int l  = t & 63;
  const int wm = (w >> 1) * 32;
  const int wn = (w & 1) * 64;
  const int fr = l & 15;
  const int kc = l >> 4;

  bf16x8 aq[2][4];
  #pragma unroll
  for (int i = 0; i < 2; ++i)
    #pragma unroll
    for (int ks = 0; ks < 4; ++ks)
      aq[i][ks] = *(const bf16x8*)(Qp + (long long)(r0g + wm + i * 16 + fr) * 6144
                                      + ks * 32 + kc * 8);

  f32x4 oacc[2][4];
  #pragma unroll
  for (int i = 0; i < 2; ++i)
    #pragma unroll
    for (int j = 0; j < 4; ++j)
      #pragma unroll
      for (int r = 0; r < 4; ++r) oacc[i][j][r] = 0.0f;
  float lsum[2][4];
  #pragma unroll
  for (int i = 0; i < 2; ++i)
    #pragma unroll
    for (int r = 0; r < 4; ++r) lsum[i][r] = 0.0f;

  for (int it = 0; it < niter; ++it) {
    const int t0 = it * 128;
    #pragma unroll
    for (int s = 0; s < 8; ++s) {
      const int chunk = (w * 8 + s) * 64 + l;
      const int r = chunk >> 4;
      const int c = (chunk & 15) ^ (r & 7);
      async16(Kp + (long long)(t0 + r) * 6144 + c * 8, &sKV[(w * 8 + s) * 512]);
    }
    __builtin_amdgcn_s_waitcnt(0);
    __syncthreads();

    f32x4 acc[2][4];
    #pragma unroll
    for (int i = 0; i < 2; ++i)
      #pragma unroll
      for (int j = 0; j < 4; ++j)
        #pragma unroll
        for (int r = 0; r < 4; ++r) acc[i][j][r] = 0.0f;
    #pragma unroll
    for (int ks = 0; ks < 4; ++ks) {
      bf16x8 bk[4];
      #pragma unroll
      for (int j = 0; j < 4; ++j) {
        const int r = wn + j * 16 + fr;
        const int c = (ks * 4 + kc) ^ (r & 7);
        bk[j] = *(const bf16x8*)&sKV[r * 128 + c * 8];
      }
      #pragma unroll
      for (int i = 0; i < 2; ++i)
        #pragma unroll
        for (int j = 0; j < 4; ++j)
          acc[i][j] = __builtin_amdgcn_mfma_f32_16x16x32_bf16(aq[i][ks], bk[j], acc[i][j], 0, 0, 0);
    }

    #pragma unroll
    for (int i = 0; i < 2; ++i) {
      #pragma unroll
      for (int r = 0; r < 4; ++r) {
        const int rowl = wm + i * 16 + kc * 4 + r;
        const int Rg = r0g + rowl;
        float rs = 0.f;
        #pragma unroll
        for (int j = 0; j < 4; ++j) {
          const int coll = wn + j * 16 + fr;
          const float e = (t0 + coll <= Rg) ? __expf(acc[i][j][r] * iscale) : 0.0f;
          rs += e;
          sP[rowl * 136 + coll] = (bf16_t)e;
        }
        rs += __shfl_xor(rs, 1, 64);
        rs += __shfl_xor(rs, 2, 64);
        rs += __shfl_xor(rs, 4, 64);
        rs += __shfl_xor(rs, 8, 64);
        if (fr == 0) sL[w & 1][rowl] = rs;
      }
    }
    __syncthreads();

    #pragma unroll
    for (int i = 0; i < 2; ++i)
      #pragma unroll
      for (int r = 0; r < 4; ++r) {
        const int rowl = wm + i * 16 + kc * 4 + r;
        lsum[i][r] += sL[0][rowl] + sL[1][rowl];
      }
    #pragma unroll
    for (int s = 0; s < 8; ++s) {
      const int chunk = (w * 8 + s) * 64 + l;
      const int r = chunk >> 4;
      const int c = (chunk & 15) ^ (r & 7);
      async16(Vp + (long long)r * 2048 + t0 + c * 8, &sKV[(w * 8 + s) * 512]);
    }
    __builtin_amdgcn_s_waitcnt(0);
    __syncthreads();

    #pragma unroll
    for (int ks = 0; ks < 4; ++ks) {
      bf16x8 ap[2], bv[4];
      #pragma unroll
      for (int i = 0; i < 2; ++i)
        ap[i] = *(const bf16x8*)&sP[(wm + i * 16 + fr) * 136 + ks * 32 + kc * 8];
      #pragma unroll
      for (int j = 0; j < 4; ++j) {
        const int r = wn + j * 16 + fr;
        const int c = (ks * 4 + kc) ^ (r & 7);
        bv[j] = *(const bf16x8*)&sKV[r * 128 + c * 8];
      }
      #pragma unroll
      for (int i = 0; i < 2; ++i)
        #pragma unroll
        for (int j = 0; j < 4; ++j)
          oacc[i][j] = __builtin_amdgcn_mfma_f32_16x16x32_bf16(ap[i], bv[j], oacc[i][j], 0, 0, 0);
    }
    __syncthreads();
  }

  #pragma unroll
  for (int i = 0; i < 2; ++i) {
    #pragma unroll
    for (int r = 0; r < 4; ++r) {
      const int rowl = wm + i * 16 + kc * 4 + r;
      const float inv = 1.0f / lsum[i][r];
      #pragma unroll
      for (int j = 0; j < 4; ++j) {
        const int coll = wn + j * 16 + fr;
        ctx[(long long)(r0g + rowl) * 2048 + h * 128 + coll] = (bf16_t)(oacc[i][j][r] * inv);
      }
    }
  }
}

// ---------------------------------------------------------------------------
// front: z-routed mega-kernel for all memory-bound prep work.
//   z in [0,2048):   f32->bf16 casts: z<1024 hs->hsb, else svd_tok->stb
//   z in [2048,2560): per-head 128x128 transposes of svd_qk/svd_vl
//   z in [2560,2816): strip transposes of qkv_w (48 blks) / dense_w (16 blks)
//   z in [2816,2840): brot (2 hp per block)
// ---------------------------------------------------------------------------
__global__ __launch_bounds__(256)
void front_k(const float* __restrict__ hs, bf16_t* __restrict__ hsb,
             const float* __restrict__ svd_tok, bf16_t* __restrict__ stb,
             const float* __restrict__ svd_qk, bf16_t* __restrict__ qkT,
             const float* __restrict__ svd_vl, bf16_t* __restrict__ vlT,
             const float* __restrict__ qkv_w, bf16_t* __restrict__ qkv_wT,
             const float* __restrict__ dense_w, bf16_t* __restrict__ dwT,
             const float* __restrict__ qkv_b, bf16_t* __restrict__ brot)
{
  __shared__ bf16_t sm[32][33];
  const int z = blockIdx.x;
  const int tid = threadIdx.x;

  if (z < 2048) {
    const float* in = (z < 1024) ? hs : svd_tok;
    bf16_t* out = (z < 1024) ? hsb : stb;
    const int base = (z & 1023) * 4096 + tid * 16;
    #pragma unroll
    for (int j = 0; j < 4; ++j) {
      const f32x4 v = *(const f32x4*)(in + base + j * 4);
      bf16x4 o;
      #pragma unroll
      for (int k = 0; k < 4; ++k) o[k] = (bf16_t)v[k];
      *(bf16x4*)(out + base + j * 4) = o;
    }
  } else if (z < 2560) {
    const int zz = z - 2048;
    const int zr = zz >> 4;                 // 0..31
    const int tile = zz & 15;
    const float* ip = (zr < 16 ? svd_qk : svd_vl) + (long long)(zr & 15) * 16384;
    bf16_t* op = (zr < 16 ? qkT : vlT) + (long long)(zr & 15) * 16384;
    const int r0 = (tile & 3) << 5;
    const int c0 = (tile >> 2) << 5;
    const int tx = tid & 31;
    const int ty = tid >> 5;
    #pragma unroll
    for (int yy = ty; yy < 32; yy += 8)
      sm[yy][tx] = (bf16_t)ip[(long long)(r0 + yy) * 128 + c0 + tx];
    __syncthreads();
    #pragma unroll
    for (int yy = ty; yy < 32; yy += 8)
      op[(long long)(c0 + yy) * 128 + r0 + tx] = sm[tx][yy];
  } else if (z < 2816) {
    const int zz = z - 2560;
    const int zb = zz >> 2;                 // 0..63
    const int rt = zz & 3;
    const float* ip = (zb < 48) ? qkv_w + (long long)zb * 262144
                                : dense_w + (long long)(zb - 48) * 262144;
    bf16_t* op = (zb < 48) ? qkv_wT + (long long)zb * 262144
                           : dwT + (long long)(zb - 48) * 262144;
    const int r0 = rt << 5;
    const int tx = tid & 31;
    const int ty = tid >> 5;
    for (int ct = 0; ct < 64; ++ct) {
      const int c0 = ct << 5;
      #pragma unroll
      for (int yy = ty; yy < 32; yy += 8)
        sm[yy][tx] = (bf16_t)ip[(long long)(r0 + yy) * 2048 + c0 + tx];
      __syncthreads();
      #pragma unroll
      for (int yy = ty; yy < 32; yy += 8)
        op[(long long)(c0 + yy) * 128 + r0 + tx] = sm[tx][yy];
      __syncthreads();
    }
  } else {
    const int hp = (z - 2816) * 2 + (tid >> 7);   // 0..47
    const int h = hp / 3, p = hp % 3;
    const int e = tid & 127;
    const float* R = (p == 2 ? (const float*)svd_vl : (const float*)svd_qk) + (long long)h * 16384;
    const float* b = qkv_b + h * 384 + p * 128;
    float acc = 0.f;
    for (int d = 0; d < 128; ++d)
      acc += b[d] * R[d * 128 + e];
    brot[h * 384 + p * 128 + e] = (bf16_t)acc;
  }
}

// bf16 -> bf16 transpose (coalesced both sides via LDS tile)
__global__ __launch_bounds__(256)
void transpose_b2b(const bf16_t* __restrict__ in, bf16_t* __restrict__ out,
                   int R, long long zsi, int rsi, long long zso)
{
  __shared__ bf16_t sm[32][33];
  const int z  = blockIdx.z;
  const int r0 = blockIdx.x << 5;
  const int c0 = blockIdx.y << 5;
  const int tx = threadIdx.x & 31;
  const int ty = threadIdx.x >> 5;
  const bf16_t* ip = in + (long long)z * zsi;
  bf16_t* op = out + (long long)z * zso;
  #pragma unroll
  for (int yy = ty; yy < 32; yy += 8)
    sm[yy][tx] = ip[(long long)(r0 + yy) * rsi + c0 + tx];
  __syncthreads();
  #pragma unroll
  for (int yy = ty; yy < 32; yy += 8)
    op[(long long)(c0 + yy) * R + r0 + tx] = sm[tx][yy];
}

extern "C" void kernel_launch(void* const* d_in, const int* in_sizes, int n_in,
                              void* d_out, int out_size, void* d_ws, size_t ws_size,
                              hipStream_t stream)
{
  const float* hs      = (const float*)d_in[0];
  const float* qkv_w   = (const float*)d_in[2];
  const float* qkv_b   = (const float*)d_in[3];
  const float* svd_tok = (const float*)d_in[4];
  const float* svd_qk  = (const float*)d_in[5];
  const float* svd_vl  = (const float*)d_in[6];
  const float* dense_w = (const float*)d_in[7];
  const float* dense_b = (const float*)d_in[8];
  float* out = (float*)d_out;
  bf16_t* ws = (bf16_t*)d_ws;

  bf16_t* hsb    = ws;                    //  4,194,304
  bf16_t* stb    = ws +  4194304LL;       //  4,194,304
  bf16_t* Mbuf   = ws +  8388608LL;       //  4,194,304
  bf16_t* x2     = ws + 12582912LL;       //  4,194,304
  bf16_t* qkv_wT = ws + 16777216LL;       // 12,582,912
  bf16_t* Wrot   = ws + 29360128LL;       // 12,582,912
  bf16_t* mixed  = ws + 41943040LL;       // 12,582,912
  bf16_t* vT     = ws + 54525952LL;       //  4,194,304
  bf16_t* ctx    = ws + 58720256LL;       //  4,194,304
  bf16_t* dwT    = ws + 62914560LL;       //  4,194,304
  bf16_t* tsrT   = ws + 67108864LL;       //  4,194,304
  bf16_t* qkT    = ws + 71303168LL;       //    262,144
  bf16_t* vlT    = ws + 71565312LL;       //    262,144
  bf16_t* brot   = ws + 71827456LL;       //      6,144
  if (ws_size < 71833600ULL * 2ULL) return;

  const float iscale = 0.08838834764831845f;   // 1/sqrt(128)

  // all memory-bound prep in one launch
  front_k<<<dim3(2840), 256, 0, stream>>>(hs, hsb, svd_tok, stb,
      svd_qk, qkT, svd_vl, vlT, qkv_w, qkv_wT, dense_w, dwT, qkv_b, brot);
  // M GEMM + Wrot/tsrT prep in one launch
  gemm_mprep<<<dim3(1536), 256, 0, stream>>>(qkT, vlT, qkv_wT, dwT,
      Wrot, tsrT, stb, Mbuf);
  // x2 = hs @ M  (M symmetric -> NT ok), BK=128
  gemm_nt64k<<<dim3(16, 32), 256, 0, stream>>>(hsb, Mbuf, x2, nullptr,
      2048, 2048, 2048, 2048, 1.0f, 0);
  // mixed = x2 @ Wrot^T + brot  (128^2 tile, BK=64)
  gemm_nt128<<<dim3(48, 16), 256, 0, stream>>>(x2, Wrot, mixed, brot,
      2048, 2048, 2048, 6144, 1.0f, 8);
  // vT[h][e][t] = mixed[t][384h+256+e]
  transpose_b2b<<<dim3(64, 4, 16), 256, 0, stream>>>(mixed + 256, vT, 2048, 384, 6144, 262144);
  // fused attention -> ctx
  flash_k<<<dim3(32, 16), 256, 0, stream>>>(mixed, vT, ctx, iscale);
  // out = ctx @ tsrT^T + dense_b  (f32 store), BK=128
  gemm_nt64k<<<dim3(16, 32), 256, 0, stream>>>(ctx, tsrT, out, dense_b,
      2048, 2048, 2048, 2048, 1.0f, 4);
}

// Round 9
// 399.074 us; speedup vs baseline: 1.2828x; 1.2828x over previous
//
#include <hip/hip_runtime.h>
#include <hip/hip_bf16.h>
#include <stdint.h>
#include <math.h>

// ---------------------------------------------------------------------------
// Attention_74852690035363 — f32 I/O, bf16 MFMA compute.
//   front = casts + all weight transposes + brot  [ONE z-routed launch,
//           fully parallel: one 32x32 tile per block]
//   Mprep = M GEMM (512 blk) + Wrot/tsrT prep (1024 blk)  [ONE launch]
//   x2    = hs·M (M symmetric)          [64x128 tile, BK=128]
//   mixed = x2·Wrotᵀ + brot             [128² tile BK=64, 768 blk]
//   vT    = transpose of V blocks of mixed
//   flash = fused exp(scale·q·kᵀ) causal / rowsum / P·V -> ctx
//   out   = ctx·tsrTᵀ + dense_b         [64x128 tile, BK=128, f32 store]
// LDS tiles 16B-chunk XOR-swizzled (verified: SQ_LDS_BANK_CONFLICT = 0).
// ---------------------------------------------------------------------------

typedef __bf16 bf16_t;
typedef __bf16 bf16x8 __attribute__((ext_vector_type(8)));
typedef __bf16 bf16x4 __attribute__((ext_vector_type(4)));
typedef float  f32x4  __attribute__((ext_vector_type(4)));

__device__ __forceinline__ void async16(const void* g, void* l) {
  __builtin_amdgcn_global_load_lds(
      (const __attribute__((address_space(1))) void*)(uintptr_t)g,
      (__attribute__((address_space(3))) void*)(uint32_t)(uintptr_t)l,
      16, 0, 0);
}

// ---------------- 128x128-tile NT GEMM, BK=64 (for `mixed`) ----------------
// flags&8: bf16 bias
__global__ __launch_bounds__(256)
void gemm_nt128(const bf16_t* __restrict__ A, const bf16_t* __restrict__ B,
                void* __restrict__ Cv, const void* __restrict__ biasv,
                int K, int lda, int ldb, int ldc, float alpha, int flags)
{
  const int bm0 = blockIdx.y * 128;
  const int bn0 = blockIdx.x * 128;

  __shared__ bf16_t shA[8192];   // 2 halves x 128x32
  __shared__ bf16_t shB[8192];

  const int t  = threadIdx.x;
  const int w  = t >> 6;
  const int l  = t & 63;
  const int wm = (w >> 1) * 64;
  const int wn = (w & 1) * 64;
  const int r0 = l >> 2;
  const int c0 = ((l & 3) ^ ((l >> 3) & 3)) * 8;
  const int fr = l & 15;
  const int kc = l >> 4;
  const int swr = ((fr >> 1) & 3);

  f32x4 acc[4][4];
  #pragma unroll
  for (int i = 0; i < 4; ++i)
    #pragma unroll
    for (int j = 0; j < 4; ++j)
      #pragma unroll
      for (int r = 0; r < 4; ++r)
        acc[i][j][r] = 0.0f;

  for (int k0 = 0; k0 < K; k0 += 64) {
    #pragma unroll
    for (int u = 0; u < 4; ++u) {
      const int seg  = u * 4 + w;
      const int half = seg >> 3;
      const int s8   = seg & 7;
      const int row  = s8 * 16 + r0;
      const int gk   = k0 + half * 32 + c0;
      async16(A + (long long)(bm0 + row) * lda + gk, &shA[half * 4096 + s8 * 512]);
      async16(B + (long long)(bn0 + row) * ldb + gk, &shB[half * 4096 + s8 * 512]);
    }
    __builtin_amdgcn_s_waitcnt(0);
    __syncthreads();

    const int rc = (kc ^ swr) * 8;
    #pragma unroll
    for (int h = 0; h < 2; ++h) {
      bf16x8 af[4], bfv[4];
      #pragma unroll
      for (int i = 0; i < 4; ++i) {
        af[i]  = *(const bf16x8*)&shA[h * 4096 + (wm + i * 16 + fr) * 32 + rc];
        bfv[i] = *(const bf16x8*)&shB[h * 4096 + (wn + i * 16 + fr) * 32 + rc];
      }
      #pragma unroll
      for (int i = 0; i < 4; ++i)
        #pragma unroll
        for (int j = 0; j < 4; ++j)
          acc[i][j] = __builtin_amdgcn_mfma_f32_16x16x32_bf16(af[i], bfv[j], acc[i][j], 0, 0, 0);
    }
    __syncthreads();
  }

  const int cc = l & 15;
  const int rq = (l >> 4) * 4;
  bf16_t* C = (bf16_t*)Cv;
  const bf16_t* bias = (flags & 8) ? (const bf16_t*)biasv : nullptr;
  #pragma unroll
  for (int j = 0; j < 4; ++j) {
    const int col = bn0 + wn + j * 16 + cc;
    const float bv = bias ? (float)bias[col] : 0.0f;
    #pragma unroll
    for (int i = 0; i < 4; ++i)
      #pragma unroll
      for (int r = 0; r < 4; ++r) {
        const int row = bm0 + wm + i * 16 + rq + r;
        C[(long long)row * ldc + col] = (bf16_t)(acc[i][j][r] * alpha + bv);
      }
  }
}

// ---------------- 64x128-tile NT GEMM, BK=128 (x2 / out) -------------------
// flags&4: f32 C + f32 bias
__global__ __launch_bounds__(256)
void gemm_nt64k(const bf16_t* __restrict__ A, const bf16_t* __restrict__ B,
                void* __restrict__ Cv, const void* __restrict__ biasv,
                int K, int lda, int ldb, int ldc, float alpha, int flags)
{
  const int bm0 = blockIdx.y * 64;
  const int bn0 = blockIdx.x * 128;

  __shared__ bf16_t shA[8192];    // 4 quarters x 64x32   (16 KB)
  __shared__ bf16_t shB[16384];   // 4 quarters x 128x32  (32 KB)

  const int t  = threadIdx.x;
  const int w  = t >> 6;
  const int l  = t & 63;
  const int wm = (w >> 1) * 32;
  const int wn = (w & 1) * 64;
  const int r0 = l >> 2;
  const int c0 = ((l & 3) ^ ((l >> 3) & 3)) * 8;
  const int fr = l & 15;
  const int kc = l >> 4;
  const int swr = ((fr >> 1) & 3);

  f32x4 acc[2][4];
  #pragma unroll
  for (int i = 0; i < 2; ++i)
    #pragma unroll
    for (int j = 0; j < 4; ++j)
      #pragma unroll
      for (int r = 0; r < 4; ++r)
        acc[i][j][r] = 0.0f;

  for (int k0 = 0; k0 < K; k0 += 128) {
    #pragma unroll
    for (int u = 0; u < 4; ++u) {          // A: 16 segs (4 quarters x 4)
      const int seg = u * 4 + w;
      const int q   = seg >> 2;
      const int s4  = seg & 3;
      async16(A + (long long)(bm0 + s4 * 16 + r0) * lda + (k0 + q * 32 + c0),
              &shA[q * 2048 + s4 * 512]);
    }
    #pragma unroll
    for (int u = 0; u < 8; ++u) {          // B: 32 segs (4 quarters x 8)
      const int seg = u * 4 + w;
      const int q   = seg >> 3;
      const int s8  = seg & 7;
      async16(B + (long long)(bn0 + s8 * 16 + r0) * ldb + (k0 + q * 32 + c0),
              &shB[q * 4096 + s8 * 512]);
    }
    __builtin_amdgcn_s_waitcnt(0);
    __syncthreads();

    const int rc = (kc ^ swr) * 8;
    #pragma unroll
    for (int q = 0; q < 4; ++q) {
      bf16x8 af[2], bfv[4];
      #pragma unroll
      for (int i = 0; i < 2; ++i)
        af[i]  = *(const bf16x8*)&shA[q * 2048 + (wm + i * 16 + fr) * 32 + rc];
      #pragma unroll
      for (int j = 0; j < 4; ++j)
        bfv[j] = *(const bf16x8*)&shB[q * 4096 + (wn + j * 16 + fr) * 32 + rc];
      #pragma unroll
      for (int i = 0; i < 2; ++i)
        #pragma unroll
        for (int j = 0; j < 4; ++j)
          acc[i][j] = __builtin_amdgcn_mfma_f32_16x16x32_bf16(af[i], bfv[j], acc[i][j], 0, 0, 0);
    }
    __syncthreads();
  }

  const int cc = l & 15;
  const int rq = (l >> 4) * 4;
  if (flags & 4) {
    float* C = (float*)Cv;
    const float* bias = (const float*)biasv;
    #pragma unroll
    for (int j = 0; j < 4; ++j) {
      const int col = bn0 + wn + j * 16 + cc;
      const float bv = bias ? bias[col] : 0.0f;
      #pragma unroll
      for (int i = 0; i < 2; ++i)
        #pragma unroll
        for (int r = 0; r < 4; ++r) {
          const int row = bm0 + wm + i * 16 + rq + r;
          C[(long long)row * ldc + col] = acc[i][j][r] * alpha + bv;
        }
    }
  } else {
    bf16_t* C = (bf16_t*)Cv;
    #pragma unroll
    for (int j = 0; j < 4; ++j) {
      const int col = bn0 + wn + j * 16 + cc;
      #pragma unroll
      for (int i = 0; i < 2; ++i)
        #pragma unroll
        for (int r = 0; r < 4; ++r) {
          const int row = bm0 + wm + i * 16 + rq + r;
          C[(long long)row * ldc + col] = (bf16_t)(acc[i][j][r] * alpha);
        }
    }
  }
}

// ---------------- merged M GEMM + prep GEMMs (one launch) ------------------
__global__ __launch_bounds__(256)
void gemm_mprep(const bf16_t* __restrict__ qkT, const bf16_t* __restrict__ vlT,
                const bf16_t* __restrict__ qkv_wT, const bf16_t* __restrict__ dwT,
                bf16_t* __restrict__ Wrot, bf16_t* __restrict__ tsrT,
                const bf16_t* __restrict__ stb, bf16_t* __restrict__ Mbuf)
{
  __shared__ bf16_t smem[16384];   // 32 KB, carved per branch
  const int z = blockIdx.x;
  const int t  = threadIdx.x;
  const int w  = t >> 6;
  const int l  = t & 63;
  const int r0 = l >> 2;
  const int c0 = ((l & 3) ^ ((l >> 3) & 3)) * 8;
  const int fr = l & 15;
  const int kc = l >> 4;
  const int swr = ((fr >> 1) & 3);
  const int cc = l & 15;
  const int rq = (l >> 4) * 4;

  if (z < 1024) {
    // ---------------- prep body: 128x128, BK=64, K=128 ----------------
    const int pz = z >> 4, px = z & 15;
    const bf16_t* A;
    const bf16_t* B;
    bf16_t* C;
    int bm0, bn0;
    if (pz < 48) {
      const int h = pz / 3, p = pz - 3 * h;
      A = (p == 2 ? vlT : qkT) + h * 16384;
      B = qkv_wT + (long long)pz * 262144;
      C = Wrot + (long long)pz * 262144;
      bm0 = 0;  bn0 = px * 128;
    } else {
      const int b = pz - 48;
      A = dwT + (long long)b * 262144;
      B = vlT + b * 16384;
      C = tsrT;
      bm0 = px * 128;  bn0 = b * 128;
    }
    bf16_t* shA = smem;          // 8192
    bf16_t* shB = smem + 8192;   // 8192
    const int wm = (w >> 1) * 64;
    const int wn = (w & 1) * 64;
    const int arow0 = (pz < 48 ? 0 : bm0);
    const int brow0 = (pz < 48 ? bn0 : 0);

    f32x4 acc[4][4];
    #pragma unroll
    for (int i = 0; i < 4; ++i)
      #pragma unroll
      for (int j = 0; j < 4; ++j)
        #pragma unroll
        for (int r = 0; r < 4; ++r)
          acc[i][j][r] = 0.0f;

    for (int k0 = 0; k0 < 128; k0 += 64) {
      #pragma unroll
      for (int u = 0; u < 4; ++u) {
        const int seg  = u * 4 + w;
        const int half = seg >> 3;
        const int s8   = seg & 7;
        const int row  = s8 * 16 + r0;
        const int gk   = k0 + half * 32 + c0;
        async16(A + (long long)(arow0 + row) * 128 + gk, &shA[half * 4096 + s8 * 512]);
        async16(B + (long long)(brow0 + row) * 128 + gk, &shB[half * 4096 + s8 * 512]);
      }
      __builtin_amdgcn_s_waitcnt(0);
      __syncthreads();

      const int rc = (kc ^ swr) * 8;
      #pragma unroll
      for (int h = 0; h < 2; ++h) {
        bf16x8 af[4], bfv[4];
        #pragma unroll
        for (int i = 0; i < 4; ++i) {
          af[i]  = *(const bf16x8*)&shA[h * 4096 + (wm + i * 16 + fr) * 32 + rc];
          bfv[i] = *(const bf16x8*)&shB[h * 4096 + (wn + i * 16 + fr) * 32 + rc];
        }
        #pragma unroll
        for (int i = 0; i < 4; ++i)
          #pragma unroll
          for (int j = 0; j < 4; ++j)
            acc[i][j] = __builtin_amdgcn_mfma_f32_16x16x32_bf16(af[i], bfv[j], acc[i][j], 0, 0, 0);
      }
      __syncthreads();
    }

    #pragma unroll
    for (int j = 0; j < 4; ++j) {
      const int col = bn0 + wn + j * 16 + cc;
      #pragma unroll
      for (int i = 0; i < 4; ++i)
        #pragma unroll
        for (int r = 0; r < 4; ++r) {
          const int row = arow0 + wm + i * 16 + rq + r;
          C[(long long)row * 2048 + col] = (bf16_t)acc[i][j][r];
        }
    }
  } else {
    // ---------------- M body: 64x128, BK=64, K=2048, stb·stbᵀ ----------
    const int m = z - 1024;
    const int bm0 = (m >> 4) * 64;
    const int bn0 = (m & 15) * 128;
    bf16_t* shA = smem;          // 4096
    bf16_t* shB = smem + 4096;   // 8192
    const int wm = (w >> 1) * 32;
    const int wn = (w & 1) * 64;

    f32x4 acc[2][4];
    #pragma unroll
    for (int i = 0; i < 2; ++i)
      #pragma unroll
      for (int j = 0; j < 4; ++j)
        #pragma unroll
        for (int r = 0; r < 4; ++r)
          acc[i][j][r] = 0.0f;

    for (int k0 = 0; k0 < 2048; k0 += 64) {
      #pragma unroll
      for (int u = 0; u < 2; ++u) {
        const int seg  = u * 4 + w;
        const int half = seg >> 2;
        const int s4   = seg & 3;
        async16(stb + (long long)(bm0 + s4 * 16 + r0) * 2048 + (k0 + half * 32 + c0),
                &shA[half * 2048 + s4 * 512]);
      }
      #pragma unroll
      for (int u = 0; u < 4; ++u) {
        const int seg  = u * 4 + w;
        const int half = seg >> 3;
        const int s8   = seg & 7;
        async16(stb + (long long)(bn0 + s8 * 16 + r0) * 2048 + (k0 + half * 32 + c0),
                &shB[half * 4096 + s8 * 512]);
      }
      __builtin_amdgcn_s_waitcnt(0);
      __syncthreads();

      const int rc = (kc ^ swr) * 8;
      #pragma unroll
      for (int h = 0; h < 2; ++h) {
        bf16x8 af[2], bfv[4];
        #pragma unroll
        for (int i = 0; i < 2; ++i)
          af[i]  = *(const bf16x8*)&shA[h * 2048 + (wm + i * 16 + fr) * 32 + rc];
        #pragma unroll
        for (int j = 0; j < 4; ++j)
          bfv[j] = *(const bf16x8*)&shB[h * 4096 + (wn + j * 16 + fr) * 32 + rc];
        #pragma unroll
        for (int i = 0; i < 2; ++i)
          #pragma unroll
          for (int j = 0; j < 4; ++j)
            acc[i][j] = __builtin_amdgcn_mfma_f32_16x16x32_bf16(af[i], bfv[j], acc[i][j], 0, 0, 0);
      }
      __syncthreads();
    }

    #pragma unroll
    for (int j = 0; j < 4; ++j) {
      const int col = bn0 + wn + j * 16 + cc;
      #pragma unroll
      for (int i = 0; i < 2; ++i)
        #pragma unroll
        for (int r = 0; r < 4; ++r) {
          const int row = bm0 + wm + i * 16 + rq + r;
          Mbuf[(long long)row * 2048 + col] = (bf16_t)acc[i][j][r];
        }
    }
  }
}

// ---------------------------------------------------------------------------
// Flash attention (verified rounds 4-8): one block = 64 q-rows x one head.
// ---------------------------------------------------------------------------
__global__ __launch_bounds__(256)
void flash_k(const bf16_t* __restrict__ mixed, const bf16_t* __restrict__ vT,
             bf16_t* __restrict__ ctx, float iscale)
{
  const int h  = blockIdx.y;
  const int qt = 31 - (int)blockIdx.x;
  const int r0g = qt * 64;
  const int niter = (qt >> 1) + 1;
  const bf16_t* Qp = mixed + h * 384;
  const bf16_t* Kp = mixed + h * 384 + 128;
  const bf16_t* Vp = vT + (long long)h * 262144;

  __shared__ bf16_t sKV[128 * 128];
  __shared__ bf16_t sP[64 * 136];
  __shared__ float  sL[2][64];

  const int t  = threadIdx.x;
  const int w  = t >> 6;
  const int l  = t & 63;
  const int wm = (w >> 1) * 32;
  const int wn = (w & 1) * 64;
  const int fr = l & 15;
  const int kc = l >> 4;

  bf16x8 aq[2][4];
  #pragma unroll
  for (int i = 0; i < 2; ++i)
    #pragma unroll
    for (int ks = 0; ks < 4; ++ks)
      aq[i][ks] = *(const bf16x8*)(Qp + (long long)(r0g + wm + i * 16 + fr) * 6144
                                      + ks * 32 + kc * 8);

  f32x4 oacc[2][4];
  #pragma unroll
  for (int i = 0; i < 2; ++i)
    #pragma unroll
    for (int j = 0; j < 4; ++j)
      #pragma unroll
      for (int r = 0; r < 4; ++r) oacc[i][j][r] = 0.0f;
  float lsum[2][4];
  #pragma unroll
  for (int i = 0; i < 2; ++i)
    #pragma unroll
    for (int r = 0; r < 4; ++r) lsum[i][r] = 0.0f;

  for (int it = 0; it < niter; ++it) {
    const int t0 = it * 128;
    #pragma unroll
    for (int s = 0; s < 8; ++s) {
      const int chunk = (w * 8 + s) * 64 + l;
      const int r = chunk >> 4;
      const int c = (chunk & 15) ^ (r & 7);
      async16(Kp + (long long)(t0 + r) * 6144 + c * 8, &sKV[(w * 8 + s) * 512]);
    }
    __builtin_amdgcn_s_waitcnt(0);
    __syncthreads();

    f32x4 acc[2][4];
    #pragma unroll
    for (int i = 0; i < 2; ++i)
      #pragma unroll
      for (int j = 0; j < 4; ++j)
        #pragma unroll
        for (int r = 0; r < 4; ++r) acc[i][j][r] = 0.0f;
    #pragma unroll
    for (int ks = 0; ks < 4; ++ks) {
      bf16x8 bk[4];
      #pragma unroll
      for (int j = 0; j < 4; ++j) {
        const int r = wn + j * 16 + fr;
        const int c = (ks * 4 + kc) ^ (r & 7);
        bk[j] = *(const bf16x8*)&sKV[r * 128 + c * 8];
      }
      #pragma unroll
      for (int i = 0; i < 2; ++i)
        #pragma unroll
        for (int j = 0; j < 4; ++j)
          acc[i][j] = __builtin_amdgcn_mfma_f32_16x16x32_bf16(aq[i][ks], bk[j], acc[i][j], 0, 0, 0);
    }

    #pragma unroll
    for (int i = 0; i < 2; ++i) {
      #pragma unroll
      for (int r = 0; r < 4; ++r) {
        const int rowl = wm + i * 16 + kc * 4 + r;
        const int Rg = r0g + rowl;
        float rs = 0.f;
        #pragma unroll
        for (int j = 0; j < 4; ++j) {
          const int coll = wn + j * 16 + fr;
          const float e = (t0 + coll <= Rg) ? __expf(acc[i][j][r] * iscale) : 0.0f;
          rs += e;
          sP[rowl * 136 + coll] = (bf16_t)e;
        }
        rs += __shfl_xor(rs, 1, 64);
        rs += __shfl_xor(rs, 2, 64);
        rs += __shfl_xor(rs, 4, 64);
        rs += __shfl_xor(rs, 8, 64);
        if (fr == 0) sL[w & 1][rowl] = rs;
      }
    }
    __syncthreads();

    #pragma unroll
    for (int i = 0; i < 2; ++i)
      #pragma unroll
      for (int r = 0; r < 4; ++r) {
        const int rowl = wm + i * 16 + kc * 4 + r;
        lsum[i][r] += sL[0][rowl] + sL[1][rowl];
      }
    #pragma unroll
    for (int s = 0; s < 8; ++s) {
      const int chunk = (w * 8 + s) * 64 + l;
      const int r = chunk >> 4;
      const int c = (chunk & 15) ^ (r & 7);
      async16(Vp + (long long)r * 2048 + t0 + c * 8, &sKV[(w * 8 + s) * 512]);
    }
    __builtin_amdgcn_s_waitcnt(0);
    __syncthreads();

    #pragma unroll
    for (int ks = 0; ks < 4; ++ks) {
      bf16x8 ap[2], bv[4];
      #pragma unroll
      for (int i = 0; i < 2; ++i)
        ap[i] = *(const bf16x8*)&sP[(wm + i * 16 + fr) * 136 + ks * 32 + kc * 8];
      #pragma unroll
      for (int j = 0; j < 4; ++j) {
        const int r = wn + j * 16 + fr;
        const int c = (ks * 4 + kc) ^ (r & 7);
        bv[j] = *(const bf16x8*)&sKV[r * 128 + c * 8];
      }
      #pragma unroll
      for (int i = 0; i < 2; ++i)
        #pragma unroll
        for (int j = 0; j < 4; ++j)
          oacc[i][j] = __builtin_amdgcn_mfma_f32_16x16x32_bf16(ap[i], bv[j], oacc[i][j], 0, 0, 0);
    }
    __syncthreads();
  }

  #pragma unroll
  for (int i = 0; i < 2; ++i) {
    #pragma unroll
    for (int r = 0; r < 4; ++r) {
      const int rowl = wm + i * 16 + kc * 4 + r;
      const float inv = 1.0f / lsum[i][r];
      #pragma unroll
      for (int j = 0; j < 4; ++j) {
        const int coll = wn + j * 16 + fr;
        ctx[(long long)(r0g + rowl) * 2048 + h * 128 + coll] = (bf16_t)(oacc[i][j][r] * inv);
      }
    }
  }
}

// ---------------------------------------------------------------------------
// front: z-routed mega-kernel, fully parallel (one tile per block).
//   z in [0,2048):        f32->bf16 casts: z<1024 hs->hsb, else svd_tok->stb
//   z in [2048,2560):     per-head 128x128 transposes of svd_qk/svd_vl
//   z in [2560,18944):    qkv_w (48) / dense_w (16) transposes,
//                         one 32x32 tile per block (64 batches x 256 tiles)
//   z in [18944,18968):   brot (2 hp per block)
// ---------------------------------------------------------------------------
__global__ __launch_bounds__(256)
void front_k(const float* __restrict__ hs, bf16_t* __restrict__ hsb,
             const float* __restrict__ svd_tok, bf16_t* __restrict__ stb,
             const float* __restrict__ svd_qk, bf16_t* __restrict__ qkT,
             const float* __restrict__ svd_vl, bf16_t* __restrict__ vlT,
             const float* __restrict__ qkv_w, bf16_t* __restrict__ qkv_wT,
             const float* __restrict__ dense_w, bf16_t* __restrict__ dwT,
             const float* __restrict__ qkv_b, bf16_t* __restrict__ brot)
{
  __shared__ bf16_t sm[32][33];
  const int z = blockIdx.x;
  const int tid = threadIdx.x;

  if (z < 2048) {
    const float* in = (z < 1024) ? hs : svd_tok;
    bf16_t* out = (z < 1024) ? hsb : stb;
    const int base = (z & 1023) * 4096 + tid * 16;
    #pragma unroll
    for (int j = 0; j < 4; ++j) {
      const f32x4 v = *(const f32x4*)(in + base + j * 4);
      bf16x4 o;
      #pragma unroll
      for (int k = 0; k < 4; ++k) o[k] = (bf16_t)v[k];
      *(bf16x4*)(out + base + j * 4) = o;
    }
  } else if (z < 2560) {
    const int zz = z - 2048;
    const int zr = zz >> 4;                 // 0..31
    const int tile = zz & 15;
    const float* ip = (zr < 16 ? svd_qk : svd_vl) + (long long)(zr & 15) * 16384;
    bf16_t* op = (zr < 16 ? qkT : vlT) + (long long)(zr & 15) * 16384;
    const int r0 = (tile & 3) << 5;
    const int c0 = (tile >> 2) << 5;
    const int tx = tid & 31;
    const int ty = tid >> 5;
    #pragma unroll
    for (int yy = ty; yy < 32; yy += 8)
      sm[yy][tx] = (bf16_t)ip[(long long)(r0 + yy) * 128 + c0 + tx];
    __syncthreads();
    #pragma unroll
    for (int yy = ty; yy < 32; yy += 8)
      op[(long long)(c0 + yy) * 128 + r0 + tx] = sm[tx][yy];
  } else if (z < 18944) {
    const int zz = z - 2560;
    const int zb = zz >> 8;                 // batch 0..63
    const int tile = zz & 255;              // 4 r-tiles x 64 c-tiles
    const float* ip = (zb < 48) ? qkv_w + (long long)zb * 262144
                                : dense_w + (long long)(zb - 48) * 262144;
    bf16_t* op = (zb < 48) ? qkv_wT + (long long)zb * 262144
                           : dwT + (long long)(zb - 48) * 262144;
    const int r0 = (tile & 3) << 5;
    const int c0 = (tile >> 2) << 5;
    const int tx = tid & 31;
    const int ty = tid >> 5;
    #pragma unroll
    for (int yy = ty; yy < 32; yy += 8)
      sm[yy][tx] = (bf16_t)ip[(long long)(r0 + yy) * 2048 + c0 + tx];
    __syncthreads();
    #pragma unroll
    for (int yy = ty; yy < 32; yy += 8)
      op[(long long)(c0 + yy) * 128 + r0 + tx] = sm[tx][yy];
  } else {
    const int hp = (z - 18944) * 2 + (tid >> 7);   // 0..47
    const int h = hp / 3, p = hp % 3;
    const int e = tid & 127;
    const float* R = (p == 2 ? (const float*)svd_vl : (const float*)svd_qk) + (long long)h * 16384;
    const float* b = qkv_b + h * 384 + p * 128;
    float acc = 0.f;
    for (int d = 0; d < 128; ++d)
      acc += b[d] * R[d * 128 + e];
    brot[h * 384 + p * 128 + e] = (bf16_t)acc;
  }
}

// bf16 -> bf16 transpose (coalesced both sides via LDS tile)
__global__ __launch_bounds__(256)
void transpose_b2b(const bf16_t* __restrict__ in, bf16_t* __restrict__ out,
                   int R, long long zsi, int rsi, long long zso)
{
  __shared__ bf16_t sm[32][33];
  const int z  = blockIdx.z;
  const int r0 = blockIdx.x << 5;
  const int c0 = blockIdx.y << 5;
  const int tx = threadIdx.x & 31;
  const int ty = threadIdx.x >> 5;
  const bf16_t* ip = in + (long long)z * zsi;
  bf16_t* op = out + (long long)z * zso;
  #pragma unroll
  for (int yy = ty; yy < 32; yy += 8)
    sm[yy][tx] = ip[(long long)(r0 + yy) * rsi + c0 + tx];
  __syncthreads();
  #pragma unroll
  for (int yy = ty; yy < 32; yy += 8)
    op[(long long)(c0 + yy) * R + r0 + tx] = sm[tx][yy];
}

extern "C" void kernel_launch(void* const* d_in, const int* in_sizes, int n_in,
                              void* d_out, int out_size, void* d_ws, size_t ws_size,
                              hipStream_t stream)
{
  const float* hs      = (const float*)d_in[0];
  const float* qkv_w   = (const float*)d_in[2];
  const float* qkv_b   = (const float*)d_in[3];
  const float* svd_tok = (const float*)d_in[4];
  const float* svd_qk  = (const float*)d_in[5];
  const float* svd_vl  = (const float*)d_in[6];
  const float* dense_w = (const float*)d_in[7];
  const float* dense_b = (const float*)d_in[8];
  float* out = (float*)d_out;
  bf16_t* ws = (bf16_t*)d_ws;

  bf16_t* hsb    = ws;                    //  4,194,304
  bf16_t* stb    = ws +  4194304LL;       //  4,194,304
  bf16_t* Mbuf   = ws +  8388608LL;       //  4,194,304
  bf16_t* x2     = ws + 12582912LL;       //  4,194,304
  bf16_t* qkv_wT = ws + 16777216LL;       // 12,582,912
  bf16_t* Wrot   = ws + 29360128LL;       // 12,582,912
  bf16_t* mixed  = ws + 41943040LL;       // 12,582,912
  bf16_t* vT     = ws + 54525952LL;       //  4,194,304
  bf16_t* ctx    = ws + 58720256LL;       //  4,194,304
  bf16_t* dwT    = ws + 62914560LL;       //  4,194,304
  bf16_t* tsrT   = ws + 67108864LL;       //  4,194,304
  bf16_t* qkT    = ws + 71303168LL;       //    262,144
  bf16_t* vlT    = ws + 71565312LL;       //    262,144
  bf16_t* brot   = ws + 71827456LL;       //      6,144
  if (ws_size < 71833600ULL * 2ULL) return;

  const float iscale = 0.08838834764831845f;   // 1/sqrt(128)

  // all memory-bound prep in one launch (one tile per block, no serial tail)
  front_k<<<dim3(18968), 256, 0, stream>>>(hs, hsb, svd_tok, stb,
      svd_qk, qkT, svd_vl, vlT, qkv_w, qkv_wT, dense_w, dwT, qkv_b, brot);
  // M GEMM + Wrot/tsrT prep in one launch
  gemm_mprep<<<dim3(1536), 256, 0, stream>>>(qkT, vlT, qkv_wT, dwT,
      Wrot, tsrT, stb, Mbuf);
  // x2 = hs @ M  (M symmetric -> NT ok), BK=128
  gemm_nt64k<<<dim3(16, 32), 256, 0, stream>>>(hsb, Mbuf, x2, nullptr,
      2048, 2048, 2048, 2048, 1.0f, 0);
  // mixed = x2 @ Wrot^T + brot  (128^2 tile, BK=64)
  gemm_nt128<<<dim3(48, 16), 256, 0, stream>>>(x2, Wrot, mixed, brot,
      2048, 2048, 2048, 6144, 1.0f, 8);
  // vT[h][e][t] = mixed[t][384h+256+e]
  transpose_b2b<<<dim3(64, 4, 16), 256, 0, stream>>>(mixed + 256, vT, 2048, 384, 6144, 262144);
  // fused attention -> ctx
  flash_k<<<dim3(32, 16), 256, 0, stream>>>(mixed, vT, ctx, iscale);
  // out = ctx @ tsrT^T + dense_b  (f32 store), BK=128
  gemm_nt64k<<<dim3(16, 32), 256, 0, stream>>>(ctx, tsrT, out, dense_b,
      2048, 2048, 2048, 2048, 1.0f, 4);
}

// Round 10
// 394.699 us; speedup vs baseline: 1.2970x; 1.0111x over previous
//
#include <hip/hip_runtime.h>
#include <hip/hip_bf16.h>
#include <stdint.h>
#include <math.h>

// ---------------------------------------------------------------------------
// Attention_74852690035363 — f32 I/O, bf16 MFMA compute.
//   front = casts + all weight transposes + brot  [ONE z-routed launch]
//   Mprep = M GEMM (512 blk) + Wrot/tsrT prep (1024 blk)  [ONE launch]
//   x2    = hs·M (M symmetric)          [64x128 tile, BK=128]
//   mixed = x2·Wrotᵀ + brot             [128² tile BK=64, 768 blk]
//   vT    = transpose of V blocks of mixed
//   flash = fused exp(scale·q·kᵀ) causal / rowsum / P·V -> ctx
//           XCD-affine grid: x=head (16) so all q-tiles of a head share an
//           XCD L2 -> K/V re-reads become L2 hits (R9: FETCH 63.6 MB, HBM-bound)
//   out   = ctx·tsrTᵀ + dense_b         [64x128 tile, BK=128, f32 store]
// LDS tiles 16B-chunk XOR-swizzled (verified: SQ_LDS_BANK_CONFLICT = 0).
// ---------------------------------------------------------------------------

typedef __bf16 bf16_t;
typedef __bf16 bf16x8 __attribute__((ext_vector_type(8)));
typedef __bf16 bf16x4 __attribute__((ext_vector_type(4)));
typedef float  f32x4  __attribute__((ext_vector_type(4)));

__device__ __forceinline__ void async16(const void* g, void* l) {
  __builtin_amdgcn_global_load_lds(
      (const __attribute__((address_space(1))) void*)(uintptr_t)g,
      (__attribute__((address_space(3))) void*)(uint32_t)(uintptr_t)l,
      16, 0, 0);
}

// ---------------- 128x128-tile NT GEMM, BK=64 (for `mixed`) ----------------
// flags&8: bf16 bias
__global__ __launch_bounds__(256)
void gemm_nt128(const bf16_t* __restrict__ A, const bf16_t* __restrict__ B,
                void* __restrict__ Cv, const void* __restrict__ biasv,
                int K, int lda, int ldb, int ldc, float alpha, int flags)
{
  const int bm0 = blockIdx.y * 128;
  const int bn0 = blockIdx.x * 128;

  __shared__ bf16_t shA[8192];   // 2 halves x 128x32
  __shared__ bf16_t shB[8192];

  const int t  = threadIdx.x;
  const int w  = t >> 6;
  const int l  = t & 63;
  const int wm = (w >> 1) * 64;
  const int wn = (w & 1) * 64;
  const int r0 = l >> 2;
  const int c0 = ((l & 3) ^ ((l >> 3) & 3)) * 8;
  const int fr = l & 15;
  const int kc = l >> 4;
  const int swr = ((fr >> 1) & 3);

  f32x4 acc[4][4];
  #pragma unroll
  for (int i = 0; i < 4; ++i)
    #pragma unroll
    for (int j = 0; j < 4; ++j)
      #pragma unroll
      for (int r = 0; r < 4; ++r)
        acc[i][j][r] = 0.0f;

  for (int k0 = 0; k0 < K; k0 += 64) {
    #pragma unroll
    for (int u = 0; u < 4; ++u) {
      const int seg  = u * 4 + w;
      const int half = seg >> 3;
      const int s8   = seg & 7;
      const int row  = s8 * 16 + r0;
      const int gk   = k0 + half * 32 + c0;
      async16(A + (long long)(bm0 + row) * lda + gk, &shA[half * 4096 + s8 * 512]);
      async16(B + (long long)(bn0 + row) * ldb + gk, &shB[half * 4096 + s8 * 512]);
    }
    __builtin_amdgcn_s_waitcnt(0);
    __syncthreads();

    const int rc = (kc ^ swr) * 8;
    #pragma unroll
    for (int h = 0; h < 2; ++h) {
      bf16x8 af[4], bfv[4];
      #pragma unroll
      for (int i = 0; i < 4; ++i) {
        af[i]  = *(const bf16x8*)&shA[h * 4096 + (wm + i * 16 + fr) * 32 + rc];
        bfv[i] = *(const bf16x8*)&shB[h * 4096 + (wn + i * 16 + fr) * 32 + rc];
      }
      #pragma unroll
      for (int i = 0; i < 4; ++i)
        #pragma unroll
        for (int j = 0; j < 4; ++j)
          acc[i][j] = __builtin_amdgcn_mfma_f32_16x16x32_bf16(af[i], bfv[j], acc[i][j], 0, 0, 0);
    }
    __syncthreads();
  }

  const int cc = l & 15;
  const int rq = (l >> 4) * 4;
  bf16_t* C = (bf16_t*)Cv;
  const bf16_t* bias = (flags & 8) ? (const bf16_t*)biasv : nullptr;
  #pragma unroll
  for (int j = 0; j < 4; ++j) {
    const int col = bn0 + wn + j * 16 + cc;
    const float bv = bias ? (float)bias[col] : 0.0f;
    #pragma unroll
    for (int i = 0; i < 4; ++i)
      #pragma unroll
      for (int r = 0; r < 4; ++r) {
        const int row = bm0 + wm + i * 16 + rq + r;
        C[(long long)row * ldc + col] = (bf16_t)(acc[i][j][r] * alpha + bv);
      }
  }
}

// ---------------- 64x128-tile NT GEMM, BK=128 (x2 / out) -------------------
// flags&4: f32 C + f32 bias
__global__ __launch_bounds__(256)
void gemm_nt64k(const bf16_t* __restrict__ A, const bf16_t* __restrict__ B,
                void* __restrict__ Cv, const void* __restrict__ biasv,
                int K, int lda, int ldb, int ldc, float alpha, int flags)
{
  const int bm0 = blockIdx.y * 64;
  const int bn0 = blockIdx.x * 128;

  __shared__ bf16_t shA[8192];    // 4 quarters x 64x32   (16 KB)
  __shared__ bf16_t shB[16384];   // 4 quarters x 128x32  (32 KB)

  const int t  = threadIdx.x;
  const int w  = t >> 6;
  const int l  = t & 63;
  const int wm = (w >> 1) * 32;
  const int wn = (w & 1) * 64;
  const int r0 = l >> 2;
  const int c0 = ((l & 3) ^ ((l >> 3) & 3)) * 8;
  const int fr = l & 15;
  const int kc = l >> 4;
  const int swr = ((fr >> 1) & 3);

  f32x4 acc[2][4];
  #pragma unroll
  for (int i = 0; i < 2; ++i)
    #pragma unroll
    for (int j = 0; j < 4; ++j)
      #pragma unroll
      for (int r = 0; r < 4; ++r)
        acc[i][j][r] = 0.0f;

  for (int k0 = 0; k0 < K; k0 += 128) {
    #pragma unroll
    for (int u = 0; u < 4; ++u) {          // A: 16 segs (4 quarters x 4)
      const int seg = u * 4 + w;
      const int q   = seg >> 2;
      const int s4  = seg & 3;
      async16(A + (long long)(bm0 + s4 * 16 + r0) * lda + (k0 + q * 32 + c0),
              &shA[q * 2048 + s4 * 512]);
    }
    #pragma unroll
    for (int u = 0; u < 8; ++u) {          // B: 32 segs (4 quarters x 8)
      const int seg = u * 4 + w;
      const int q   = seg >> 3;
      const int s8  = seg & 7;
      async16(B + (long long)(bn0 + s8 * 16 + r0) * ldb + (k0 + q * 32 + c0),
              &shB[q * 4096 + s8 * 512]);
    }
    __builtin_amdgcn_s_waitcnt(0);
    __syncthreads();

    const int rc = (kc ^ swr) * 8;
    #pragma unroll
    for (int q = 0; q < 4; ++q) {
      bf16x8 af[2], bfv[4];
      #pragma unroll
      for (int i = 0; i < 2; ++i)
        af[i]  = *(const bf16x8*)&shA[q * 2048 + (wm + i * 16 + fr) * 32 + rc];
      #pragma unroll
      for (int j = 0; j < 4; ++j)
        bfv[j] = *(const bf16x8*)&shB[q * 4096 + (wn + j * 16 + fr) * 32 + rc];
      #pragma unroll
      for (int i = 0; i < 2; ++i)
        #pragma unroll
        for (int j = 0; j < 4; ++j)
          acc[i][j] = __builtin_amdgcn_mfma_f32_16x16x32_bf16(af[i], bfv[j], acc[i][j], 0, 0, 0);
    }
    __syncthreads();
  }

  const int cc = l & 15;
  const int rq = (l >> 4) * 4;
  if (flags & 4) {
    float* C = (float*)Cv;
    const float* bias = (const float*)biasv;
    #pragma unroll
    for (int j = 0; j < 4; ++j) {
      const int col = bn0 + wn + j * 16 + cc;
      const float bv = bias ? bias[col] : 0.0f;
      #pragma unroll
      for (int i = 0; i < 2; ++i)
        #pragma unroll
        for (int r = 0; r < 4; ++r) {
          const int row = bm0 + wm + i * 16 + rq + r;
          C[(long long)row * ldc + col] = acc[i][j][r] * alpha + bv;
        }
    }
  } else {
    bf16_t* C = (bf16_t*)Cv;
    #pragma unroll
    for (int j = 0; j < 4; ++j) {
      const int col = bn0 + wn + j * 16 + cc;
      #pragma unroll
      for (int i = 0; i < 2; ++i)
        #pragma unroll
        for (int r = 0; r < 4; ++r) {
          const int row = bm0 + wm + i * 16 + rq + r;
          C[(long long)row * ldc + col] = (bf16_t)(acc[i][j][r] * alpha);
        }
    }
  }
}

// ---------------- merged M GEMM + prep GEMMs (one launch) ------------------
__global__ __launch_bounds__(256)
void gemm_mprep(const bf16_t* __restrict__ qkT, const bf16_t* __restrict__ vlT,
                const bf16_t* __restrict__ qkv_wT, const bf16_t* __restrict__ dwT,
                bf16_t* __restrict__ Wrot, bf16_t* __restrict__ tsrT,
                const bf16_t* __restrict__ stb, bf16_t* __restrict__ Mbuf)
{
  __shared__ bf16_t smem[16384];   // 32 KB, carved per branch
  const int z = blockIdx.x;
  const int t  = threadIdx.x;
  const int w  = t >> 6;
  const int l  = t & 63;
  const int r0 = l >> 2;
  const int c0 = ((l & 3) ^ ((l >> 3) & 3)) * 8;
  const int fr = l & 15;
  const int kc = l >> 4;
  const int swr = ((fr >> 1) & 3);
  const int cc = l & 15;
  const int rq = (l >> 4) * 4;

  if (z < 1024) {
    // ---------------- prep body: 128x128, BK=64, K=128 ----------------
    const int pz = z >> 4, px = z & 15;
    const bf16_t* A;
    const bf16_t* B;
    bf16_t* C;
    int bm0, bn0;
    if (pz < 48) {
      const int h = pz / 3, p = pz - 3 * h;
      A = (p == 2 ? vlT : qkT) + h * 16384;
      B = qkv_wT + (long long)pz * 262144;
      C = Wrot + (long long)pz * 262144;
      bm0 = 0;  bn0 = px * 128;
    } else {
      const int b = pz - 48;
      A = dwT + (long long)b * 262144;
      B = vlT + b * 16384;
      C = tsrT;
      bm0 = px * 128;  bn0 = b * 128;
    }
    bf16_t* shA = smem;          // 8192
    bf16_t* shB = smem + 8192;   // 8192
    const int wm = (w >> 1) * 64;
    const int wn = (w & 1) * 64;
    const int arow0 = (pz < 48 ? 0 : bm0);
    const int brow0 = (pz < 48 ? bn0 : 0);

    f32x4 acc[4][4];
    #pragma unroll
    for (int i = 0; i < 4; ++i)
      #pragma unroll
      for (int j = 0; j < 4; ++j)
        #pragma unroll
        for (int r = 0; r < 4; ++r)
          acc[i][j][r] = 0.0f;

    for (int k0 = 0; k0 < 128; k0 += 64) {
      #pragma unroll
      for (int u = 0; u < 4; ++u) {
        const int seg  = u * 4 + w;
        const int half = seg >> 3;
        const int s8   = seg & 7;
        const int row  = s8 * 16 + r0;
        const int gk   = k0 + half * 32 + c0;
        async16(A + (long long)(arow0 + row) * 128 + gk, &shA[half * 4096 + s8 * 512]);
        async16(B + (long long)(brow0 + row) * 128 + gk, &shB[half * 4096 + s8 * 512]);
      }
      __builtin_amdgcn_s_waitcnt(0);
      __syncthreads();

      const int rc = (kc ^ swr) * 8;
      #pragma unroll
      for (int h = 0; h < 2; ++h) {
        bf16x8 af[4], bfv[4];
        #pragma unroll
        for (int i = 0; i < 4; ++i) {
          af[i]  = *(const bf16x8*)&shA[h * 4096 + (wm + i * 16 + fr) * 32 + rc];
          bfv[i] = *(const bf16x8*)&shB[h * 4096 + (wn + i * 16 + fr) * 32 + rc];
        }
        #pragma unroll
        for (int i = 0; i < 4; ++i)
          #pragma unroll
          for (int j = 0; j < 4; ++j)
            acc[i][j] = __builtin_amdgcn_mfma_f32_16x16x32_bf16(af[i], bfv[j], acc[i][j], 0, 0, 0);
      }
      __syncthreads();
    }

    #pragma unroll
    for (int j = 0; j < 4; ++j) {
      const int col = bn0 + wn + j * 16 + cc;
      #pragma unroll
      for (int i = 0; i < 4; ++i)
        #pragma unroll
        for (int r = 0; r < 4; ++r) {
          const int row = arow0 + wm + i * 16 + rq + r;
          C[(long long)row * 2048 + col] = (bf16_t)acc[i][j][r];
        }
    }
  } else {
    // ---------------- M body: 64x128, BK=64, K=2048, stb·stbᵀ ----------
    const int m = z - 1024;
    const int bm0 = (m >> 4) * 64;
    const int bn0 = (m & 15) * 128;
    bf16_t* shA = smem;          // 4096
    bf16_t* shB = smem + 4096;   // 8192
    const int wm = (w >> 1) * 32;
    const int wn = (w & 1) * 64;

    f32x4 acc[2][4];
    #pragma unroll
    for (int i = 0; i < 2; ++i)
      #pragma unroll
      for (int j = 0; j < 4; ++j)
        #pragma unroll
        for (int r = 0; r < 4; ++r)
          acc[i][j][r] = 0.0f;

    for (int k0 = 0; k0 < 2048; k0 += 64) {
      #pragma unroll
      for (int u = 0; u < 2; ++u) {
        const int seg  = u * 4 + w;
        const int half = seg >> 2;
        const int s4   = seg & 3;
        async16(stb + (long long)(bm0 + s4 * 16 + r0) * 2048 + (k0 + half * 32 + c0),
                &shA[half * 2048 + s4 * 512]);
      }
      #pragma unroll
      for (int u = 0; u < 4; ++u) {
        const int seg  = u * 4 + w;
        const int half = seg >> 3;
        const int s8   = seg & 7;
        async16(stb + (long long)(bn0 + s8 * 16 + r0) * 2048 + (k0 + half * 32 + c0),
                &shB[half * 4096 + s8 * 512]);
      }
      __builtin_amdgcn_s_waitcnt(0);
      __syncthreads();

      const int rc = (kc ^ swr) * 8;
      #pragma unroll
      for (int h = 0; h < 2; ++h) {
        bf16x8 af[2], bfv[4];
        #pragma unroll
        for (int i = 0; i < 2; ++i)
          af[i]  = *(const bf16x8*)&shA[h * 2048 + (wm + i * 16 + fr) * 32 + rc];
        #pragma unroll
        for (int j = 0; j < 4; ++j)
          bfv[j] = *(const bf16x8*)&shB[h * 4096 + (wn + j * 16 + fr) * 32 + rc];
        #pragma unroll
        for (int i = 0; i < 2; ++i)
          #pragma unroll
          for (int j = 0; j < 4; ++j)
            acc[i][j] = __builtin_amdgcn_mfma_f32_16x16x32_bf16(af[i], bfv[j], acc[i][j], 0, 0, 0);
      }
      __syncthreads();
    }

    #pragma unroll
    for (int j = 0; j < 4; ++j) {
      const int col = bn0 + wn + j * 16 + cc;
      #pragma unroll
      for (int i = 0; i < 2; ++i)
        #pragma unroll
        for (int r = 0; r < 4; ++r) {
          const int row = bm0 + wm + i * 16 + rq + r;
          Mbuf[(long long)row * 2048 + col] = (bf16_t)acc[i][j][r];
        }
    }
  }
}

// ---------------------------------------------------------------------------
// Flash attention: one block = 64 q-rows x one head.
// Grid (x=head=16, y=qidx=32): linear id = h + 16*q -> XCD = h%8 under
// round-robin assignment; all q-tiles of a head share one XCD L2, so K/V
// re-reads hit L2 instead of HBM. qt = 31-y keeps long-first dispatch.
// ---------------------------------------------------------------------------
__global__ __launch_bounds__(256)
void flash_k(const bf16_t* __restrict__ mixed, const bf16_t* __restrict__ vT,
             bf16_t* __restrict__ ctx, float iscale)
{
  const int h  = blockIdx.x;
  const int qt = 31 - (int)blockIdx.y;
  const int r0g = qt * 64;
  const int niter = (qt >> 1) + 1;
  const bf16_t* Qp = mixed + h * 384;
  const bf16_t* Kp = mixed + h * 384 + 128;
  const bf16_t* Vp = vT + (long long)h * 262144;

  __shared__ bf16_t sKV[128 * 128];
  __shared__ bf16_t sP[64 * 136];
  __shared__ float  sL[2][64];

  const int t  = threadIdx.x;
  const int w  = t >> 6;
  const int l  = t & 63;
  const int wm = (w >> 1) * 32;
  const int wn = (w & 1) * 64;
  const int fr = l & 15;
  const int kc = l >> 4;

  bf16x8 aq[2][4];
  #pragma unroll
  for (int i = 0; i < 2; ++i)
    #pragma unroll
    for (int ks = 0; ks < 4; ++ks)
      aq[i][ks] = *(const bf16x8*)(Qp + (long long)(r0g + wm + i * 16 + fr) * 6144
                                      + ks * 32 + kc * 8);

  f32x4 oacc[2][4];
  #pragma unroll
  for (int i = 0; i < 2; ++i)
    #pragma unroll
    for (int j = 0; j < 4; ++j)
      #pragma unroll
      for (int r = 0; r < 4; ++r) oacc[i][j][r] = 0.0f;
  float lsum[2][4];
  #pragma unroll
  for (int i = 0; i < 2; ++i)
    #pragma unroll
    for (int r = 0; r < 4; ++r) lsum[i][r] = 0.0f;

  for (int it = 0; it < niter; ++it) {
    const int t0 = it * 128;
    #pragma unroll
    for (int s = 0; s < 8; ++s) {
      const int chunk = (w * 8 + s) * 64 + l;
      const int r = chunk >> 4;
      const int c = (chunk & 15) ^ (r & 7);
      async16(Kp + (long long)(t0 + r) * 6144 + c * 8, &sKV[(w * 8 + s) * 512]);
    }
    __builtin_amdgcn_s_waitcnt(0);
    __syncthreads();

    f32x4 acc[2][4];
    #pragma unroll
    for (int i = 0; i < 2; ++i)
      #pragma unroll
      for (int j = 0; j < 4; ++j)
        #pragma unroll
        for (int r = 0; r < 4; ++r) acc[i][j][r] = 0.0f;
    #pragma unroll
    for (int ks = 0; ks < 4; ++ks) {
      bf16x8 bk[4];
      #pragma unroll
      for (int j = 0; j < 4; ++j) {
        const int r = wn + j * 16 + fr;
        const int c = (ks * 4 + kc) ^ (r & 7);
        bk[j] = *(const bf16x8*)&sKV[r * 128 + c * 8];
      }
      #pragma unroll
      for (int i = 0; i < 2; ++i)
        #pragma unroll
        for (int j = 0; j < 4; ++j)
          acc[i][j] = __builtin_amdgcn_mfma_f32_16x16x32_bf16(aq[i][ks], bk[j], acc[i][j], 0, 0, 0);
    }

    #pragma unroll
    for (int i = 0; i < 2; ++i) {
      #pragma unroll
      for (int r = 0; r < 4; ++r) {
        const int rowl = wm + i * 16 + kc * 4 + r;
        const int Rg = r0g + rowl;
        float rs = 0.f;
        #pragma unroll
        for (int j = 0; j < 4; ++j) {
          const int coll = wn + j * 16 + fr;
          const float e = (t0 + coll <= Rg) ? __expf(acc[i][j][r] * iscale) : 0.0f;
          rs += e;
          sP[rowl * 136 + coll] = (bf16_t)e;
        }
        rs += __shfl_xor(rs, 1, 64);
        rs += __shfl_xor(rs, 2, 64);
        rs += __shfl_xor(rs, 4, 64);
        rs += __shfl_xor(rs, 8, 64);
        if (fr == 0) sL[w & 1][rowl] = rs;
      }
    }
    __syncthreads();

    #pragma unroll
    for (int i = 0; i < 2; ++i)
      #pragma unroll
      for (int r = 0; r < 4; ++r) {
        const int rowl = wm + i * 16 + kc * 4 + r;
        lsum[i][r] += sL[0][rowl] + sL[1][rowl];
      }
    #pragma unroll
    for (int s = 0; s < 8; ++s) {
      const int chunk = (w * 8 + s) * 64 + l;
      const int r = chunk >> 4;
      const int c = (chunk & 15) ^ (r & 7);
      async16(Vp + (long long)r * 2048 + t0 + c * 8, &sKV[(w * 8 + s) * 512]);
    }
    __builtin_amdgcn_s_waitcnt(0);
    __syncthreads();

    #pragma unroll
    for (int ks = 0; ks < 4; ++ks) {
      bf16x8 ap[2], bv[4];
      #pragma unroll
      for (int i = 0; i < 2; ++i)
        ap[i] = *(const bf16x8*)&sP[(wm + i * 16 + fr) * 136 + ks * 32 + kc * 8];
      #pragma unroll
      for (int j = 0; j < 4; ++j) {
        const int r = wn + j * 16 + fr;
        const int c = (ks * 4 + kc) ^ (r & 7);
        bv[j] = *(const bf16x8*)&sKV[r * 128 + c * 8];
      }
      #pragma unroll
      for (int i = 0; i < 2; ++i)
        #pragma unroll
        for (int j = 0; j < 4; ++j)
          oacc[i][j] = __builtin_amdgcn_mfma_f32_16x16x32_bf16(ap[i], bv[j], oacc[i][j], 0, 0, 0);
    }
    __syncthreads();
  }

  #pragma unroll
  for (int i = 0; i < 2; ++i) {
    #pragma unroll
    for (int r = 0; r < 4; ++r) {
      const int rowl = wm + i * 16 + kc * 4 + r;
      const float inv = 1.0f / lsum[i][r];
      #pragma unroll
      for (int j = 0; j < 4; ++j) {
        const int coll = wn + j * 16 + fr;
        ctx[(long long)(r0g + rowl) * 2048 + h * 128 + coll] = (bf16_t)(oacc[i][j][r] * inv);
      }
    }
  }
}

// ---------------------------------------------------------------------------
// front: z-routed mega-kernel, fully parallel (one tile per block).
// ---------------------------------------------------------------------------
__global__ __launch_bounds__(256)
void front_k(const float* __restrict__ hs, bf16_t* __restrict__ hsb,
             const float* __restrict__ svd_tok, bf16_t* __restrict__ stb,
             const float* __restrict__ svd_qk, bf16_t* __restrict__ qkT,
             const float* __restrict__ svd_vl, bf16_t* __restrict__ vlT,
             const float* __restrict__ qkv_w, bf16_t* __restrict__ qkv_wT,
             const float* __restrict__ dense_w, bf16_t* __restrict__ dwT,
             const float* __restrict__ qkv_b, bf16_t* __restrict__ brot)
{
  __shared__ bf16_t sm[32][33];
  const int z = blockIdx.x;
  const int tid = threadIdx.x;

  if (z < 2048) {
    const float* in = (z < 1024) ? hs : svd_tok;
    bf16_t* out = (z < 1024) ? hsb : stb;
    const int base = (z & 1023) * 4096 + tid * 16;
    #pragma unroll
    for (int j = 0; j < 4; ++j) {
      const f32x4 v = *(const f32x4*)(in + base + j * 4);
      bf16x4 o;
      #pragma unroll
      for (int k = 0; k < 4; ++k) o[k] = (bf16_t)v[k];
      *(bf16x4*)(out + base + j * 4) = o;
    }
  } else if (z < 2560) {
    const int zz = z - 2048;
    const int zr = zz >> 4;                 // 0..31
    const int tile = zz & 15;
    const float* ip = (zr < 16 ? svd_qk : svd_vl) + (long long)(zr & 15) * 16384;
    bf16_t* op = (zr < 16 ? qkT : vlT) + (long long)(zr & 15) * 16384;
    const int r0 = (tile & 3) << 5;
    const int c0 = (tile >> 2) << 5;
    const int tx = tid & 31;
    const int ty = tid >> 5;
    #pragma unroll
    for (int yy = ty; yy < 32; yy += 8)
      sm[yy][tx] = (bf16_t)ip[(long long)(r0 + yy) * 128 + c0 + tx];
    __syncthreads();
    #pragma unroll
    for (int yy = ty; yy < 32; yy += 8)
      op[(long long)(c0 + yy) * 128 + r0 + tx] = sm[tx][yy];
  } else if (z < 18944) {
    const int zz = z - 2560;
    const int zb = zz >> 8;                 // batch 0..63
    const int tile = zz & 255;              // 4 r-tiles x 64 c-tiles
    const float* ip = (zb < 48) ? qkv_w + (long long)zb * 262144
                                : dense_w + (long long)(zb - 48) * 262144;
    bf16_t* op = (zb < 48) ? qkv_wT + (long long)zb * 262144
                           : dwT + (long long)(zb - 48) * 262144;
    const int r0 = (tile & 3) << 5;
    const int c0 = (tile >> 2) << 5;
    const int tx = tid & 31;
    const int ty = tid >> 5;
    #pragma unroll
    for (int yy = ty; yy < 32; yy += 8)
      sm[yy][tx] = (bf16_t)ip[(long long)(r0 + yy) * 2048 + c0 + tx];
    __syncthreads();
    #pragma unroll
    for (int yy = ty; yy < 32; yy += 8)
      op[(long long)(c0 + yy) * 128 + r0 + tx] = sm[tx][yy];
  } else {
    const int hp = (z - 18944) * 2 + (tid >> 7);   // 0..47
    const int h = hp / 3, p = hp % 3;
    const int e = tid & 127;
    const float* R = (p == 2 ? (const float*)svd_vl : (const float*)svd_qk) + (long long)h * 16384;
    const float* b = qkv_b + h * 384 + p * 128;
    float acc = 0.f;
    for (int d = 0; d < 128; ++d)
      acc += b[d] * R[d * 128 + e];
    brot[h * 384 + p * 128 + e] = (bf16_t)acc;
  }
}

// bf16 -> bf16 transpose (coalesced both sides via LDS tile)
__global__ __launch_bounds__(256)
void transpose_b2b(const bf16_t* __restrict__ in, bf16_t* __restrict__ out,
                   int R, long long zsi, int rsi, long long zso)
{
  __shared__ bf16_t sm[32][33];
  const int z  = blockIdx.z;
  const int r0 = blockIdx.x << 5;
  const int c0 = blockIdx.y << 5;
  const int tx = threadIdx.x & 31;
  const int ty = threadIdx.x >> 5;
  const bf16_t* ip = in + (long long)z * zsi;
  bf16_t* op = out + (long long)z * zso;
  #pragma unroll
  for (int yy = ty; yy < 32; yy += 8)
    sm[yy][tx] = ip[(long long)(r0 + yy) * rsi + c0 + tx];
  __syncthreads();
  #pragma unroll
  for (int yy = ty; yy < 32; yy += 8)
    op[(long long)(c0 + yy) * R + r0 + tx] = sm[tx][yy];
}

extern "C" void kernel_launch(void* const* d_in, const int* in_sizes, int n_in,
                              void* d_out, int out_size, void* d_ws, size_t ws_size,
                              hipStream_t stream)
{
  const float* hs      = (const float*)d_in[0];
  const float* qkv_w   = (const float*)d_in[2];
  const float* qkv_b   = (const float*)d_in[3];
  const float* svd_tok = (const float*)d_in[4];
  const float* svd_qk  = (const float*)d_in[5];
  const float* svd_vl  = (const float*)d_in[6];
  const float* dense_w = (const float*)d_in[7];
  const float* dense_b = (const float*)d_in[8];
  float* out = (float*)d_out;
  bf16_t* ws = (bf16_t*)d_ws;

  bf16_t* hsb    = ws;                    //  4,194,304
  bf16_t* stb    = ws +  4194304LL;       //  4,194,304
  bf16_t* Mbuf   = ws +  8388608LL;       //  4,194,304
  bf16_t* x2     = ws + 12582912LL;       //  4,194,304
  bf16_t* qkv_wT = ws + 16777216LL;       // 12,582,912
  bf16_t* Wrot   = ws + 29360128LL;       // 12,582,912
  bf16_t* mixed  = ws + 41943040LL;       // 12,582,912
  bf16_t* vT     = ws + 54525952LL;       //  4,194,304
  bf16_t* ctx    = ws + 58720256LL;       //  4,194,304
  bf16_t* dwT    = ws + 62914560LL;       //  4,194,304
  bf16_t* tsrT   = ws + 67108864LL;       //  4,194,304
  bf16_t* qkT    = ws + 71303168LL;       //    262,144
  bf16_t* vlT    = ws + 71565312LL;       //    262,144
  bf16_t* brot   = ws + 71827456LL;       //      6,144
  if (ws_size < 71833600ULL * 2ULL) return;

  const float iscale = 0.08838834764831845f;   // 1/sqrt(128)

  // all memory-bound prep in one launch (one tile per block, no serial tail)
  front_k<<<dim3(18968), 256, 0, stream>>>(hs, hsb, svd_tok, stb,
      svd_qk, qkT, svd_vl, vlT, qkv_w, qkv_wT, dense_w, dwT, qkv_b, brot);
  // M GEMM + Wrot/tsrT prep in one launch
  gemm_mprep<<<dim3(1536), 256, 0, stream>>>(qkT, vlT, qkv_wT, dwT,
      Wrot, tsrT, stb, Mbuf);
  // x2 = hs @ M  (M symmetric -> NT ok), BK=128
  gemm_nt64k<<<dim3(16, 32), 256, 0, stream>>>(hsb, Mbuf, x2, nullptr,
      2048, 2048, 2048, 2048, 1.0f, 0);
  // mixed = x2 @ Wrot^T + brot  (128^2 tile, BK=64)
  gemm_nt128<<<dim3(48, 16), 256, 0, stream>>>(x2, Wrot, mixed, brot,
      2048, 2048, 2048, 6144, 1.0f, 8);
  // vT[h][e][t] = mixed[t][384h+256+e]
  transpose_b2b<<<dim3(64, 4, 16), 256, 0, stream>>>(mixed + 256, vT, 2048, 384, 6144, 262144);
  // fused attention -> ctx (XCD-affine: x=head, y=q-tile, long-first)
  flash_k<<<dim3(16, 32), 256, 0, stream>>>(mixed, vT, ctx, iscale);
  // out = ctx @ tsrT^T + dense_b  (f32 store), BK=128
  gemm_nt64k<<<dim3(16, 32), 256, 0, stream>>>(ctx, tsrT, out, dense_b,
      2048, 2048, 2048, 2048, 1.0f, 4);
}